// Round 1
// baseline (1144.869 us; speedup 1.0000x reference)
//
#include <hip/hip_runtime.h>
#include <math.h>

#define NN 50000
#define NF 512
#define NHID 256
#define NCLASS 64
#define NHEADS 8

// ---------------- CSR build ----------------
__global__ void k_init_deg(int* deg) {
  int i = blockIdx.x * blockDim.x + threadIdx.x;
  if (i < NN) deg[i] = 1;  // self loop
}

__global__ void k_count(const int* __restrict__ dst, int E0, int* deg) {
  int i = blockIdx.x * blockDim.x + threadIdx.x;
  if (i < E0) atomicAdd(&deg[dst[i]], 1);
}

__global__ void k_scan(const int* __restrict__ deg, int* offs, int* cursor) {
  __shared__ int sdata[1024];
  __shared__ int srun;
  int tid = threadIdx.x;
  if (tid == 0) srun = 0;
  __syncthreads();
  for (int base = 0; base < NN; base += 1024) {
    int i = base + tid;
    int v = (i < NN) ? deg[i] : 0;
    sdata[tid] = v;
    __syncthreads();
    #pragma unroll
    for (int off = 1; off < 1024; off <<= 1) {
      int t = (tid >= off) ? sdata[tid - off] : 0;
      __syncthreads();
      sdata[tid] += t;
      __syncthreads();
    }
    int incl = sdata[tid];
    int run = srun;
    if (i < NN) { offs[i] = run + incl - v; cursor[i] = run + incl - v; }
    __syncthreads();
    if (tid == 1023) srun = run + incl;
    __syncthreads();
  }
  if (tid == 0) offs[NN] = srun;
}

__global__ void k_scatter(const int* __restrict__ src, const int* __restrict__ dst,
                          int E0, int* cursor, int* __restrict__ nbr) {
  int i = blockIdx.x * blockDim.x + threadIdx.x;
  if (i < E0) {
    int pos = atomicAdd(&cursor[dst[i]], 1);
    nbr[pos] = src[i];
  } else if (i < E0 + NN) {
    int v = i - E0;
    int pos = atomicAdd(&cursor[v], 1);
    nbr[pos] = v;
  }
}

// ---------------- fp32 tiled GEMM: C[rows,cols] = A[rows,K] * B[K,cols] ----------------
__global__ __launch_bounds__(256) void k_gemm(const float* __restrict__ A,
                                              const float* __restrict__ B,
                                              float* __restrict__ C,
                                              int rows, int K, int cols) {
  __shared__ float As[16][68];  // [k][row-in-tile], pad 68 -> 2-way banks only
  __shared__ float Bs[16][68];  // [k][col-in-tile]
  int t = threadIdx.x;
  int rowBase = blockIdx.x * 64;
  int colBase = blockIdx.y * 64;
  int tx = t & 15, ty = t >> 4;
  int ar = t >> 2, ak = (t & 3) << 2;   // A-load: row ar, k-offset ak (float4 along k)
  int bk = t >> 4, bc = (t & 15) << 2;  // B-load: k row bk, col bc (float4 along cols)
  int arow = rowBase + ar;
  bool avalid = arow < rows;
  const float* Ap = A + (size_t)(avalid ? arow : 0) * K + ak;
  const float* Bp = B + (size_t)bk * cols + colBase + bc;
  float acc[4][4] = {};
  for (int k0 = 0; k0 < K; k0 += 16) {
    float4 av = avalid ? *(const float4*)(Ap + k0) : make_float4(0.f, 0.f, 0.f, 0.f);
    float4 bv = *(const float4*)(Bp + (size_t)k0 * cols);
    As[ak + 0][ar] = av.x;
    As[ak + 1][ar] = av.y;
    As[ak + 2][ar] = av.z;
    As[ak + 3][ar] = av.w;
    *(float4*)&Bs[bk][bc] = bv;
    __syncthreads();
    #pragma unroll
    for (int kk = 0; kk < 16; kk++) {
      float4 a4 = *(const float4*)&As[kk][ty << 2];
      float4 b4 = *(const float4*)&Bs[kk][tx << 2];
      acc[0][0] += a4.x * b4.x; acc[0][1] += a4.x * b4.y; acc[0][2] += a4.x * b4.z; acc[0][3] += a4.x * b4.w;
      acc[1][0] += a4.y * b4.x; acc[1][1] += a4.y * b4.y; acc[1][2] += a4.y * b4.z; acc[1][3] += a4.y * b4.w;
      acc[2][0] += a4.z * b4.x; acc[2][1] += a4.z * b4.y; acc[2][2] += a4.z * b4.z; acc[2][3] += a4.z * b4.w;
      acc[3][0] += a4.w * b4.x; acc[3][1] += a4.w * b4.y; acc[3][2] += a4.w * b4.z; acc[3][3] += a4.w * b4.w;
    }
    __syncthreads();
  }
  #pragma unroll
  for (int i = 0; i < 4; i++) {
    int r = rowBase + (ty << 2) + i;
    if (r < rows) {
      float4 o = make_float4(acc[i][0], acc[i][1], acc[i][2], acc[i][3]);
      *(float4*)(C + (size_t)r * cols + colBase + (tx << 2)) = o;
    }
  }
}

// ---------------- edge-score dots: es/ed[n,h] = sum_c h[n,h,c]*a[h,c] ----------------
template <int C>
__global__ void k_escore(const float* __restrict__ h, const float* __restrict__ asr,
                         const float* __restrict__ ads, float* __restrict__ es,
                         float* __restrict__ ed) {
  int idx = blockIdx.x * blockDim.x + threadIdx.x;  // n*8 + head
  if (idx >= NN * NHEADS) return;
  int hd = idx & 7;
  const float* row = h + (size_t)idx * C;  // == n*(8*C) + hd*C
  float s = 0.f, d = 0.f;
  #pragma unroll
  for (int c = 0; c < C; c++) {
    float v = row[c];
    s += v * asr[hd * C + c];
    d += v * ads[hd * C + c];
  }
  es[idx] = s;
  ed[idx] = d;
}

// ---------------- layer-1 aggregation: wave per node, online softmax ----------------
// lane i owns channels [4i,4i+3] of the 256-wide concat output; head = lane/8.
__global__ __launch_bounds__(256) void k_agg1(const int* __restrict__ offs,
                                              const int* __restrict__ nbr,
                                              const float* __restrict__ h1,
                                              const float* __restrict__ es,
                                              const float* __restrict__ ed,
                                              const float* __restrict__ b1,
                                              float* __restrict__ out) {
  int node = blockIdx.x * 4 + (threadIdx.x >> 6);
  if (node >= NN) return;
  int lane = threadIdx.x & 63;
  int head = lane >> 3;
  int beg = offs[node], end = offs[node + 1];
  float edst = ed[node * NHEADS + head];
  float m = -INFINITY, z = 0.f;
  float4 acc = make_float4(0.f, 0.f, 0.f, 0.f);
  for (int k = beg; k < end; k++) {
    int s = nbr[k];
    float a = es[s * NHEADS + head] + edst;
    a = (a > 0.f) ? a : 0.2f * a;
    float mn = fmaxf(m, a);
    float sc = __expf(m - mn);   // first iter: exp(-inf)=0
    float w = __expf(a - mn);
    float4 v = *(const float4*)(h1 + (size_t)s * NHID + (lane << 2));
    acc.x = acc.x * sc + w * v.x;
    acc.y = acc.y * sc + w * v.y;
    acc.z = acc.z * sc + w * v.z;
    acc.w = acc.w * sc + w * v.w;
    z = z * sc + w;
    m = mn;
  }
  float inv = 1.f / z;
  int col = lane << 2;
  float4 o;
  o.x = fmaxf(acc.x * inv + b1[col + 0], 0.f);
  o.y = fmaxf(acc.y * inv + b1[col + 1], 0.f);
  o.z = fmaxf(acc.z * inv + b1[col + 2], 0.f);
  o.w = fmaxf(acc.w * inv + b1[col + 3], 0.f);
  *(float4*)(out + (size_t)node * NHID + col) = o;
}

// ---------------- layer-2 aggregation + head-mean + bias + log_softmax ----------------
// lane = class (64); each lane tracks all 8 heads (m,z,acc replicated per lane).
__global__ __launch_bounds__(256) void k_agg2(const int* __restrict__ offs,
                                              const int* __restrict__ nbr,
                                              const float* __restrict__ h2,
                                              const float* __restrict__ es,
                                              const float* __restrict__ ed,
                                              const float* __restrict__ b2,
                                              float* __restrict__ out) {
  int node = blockIdx.x * 4 + (threadIdx.x >> 6);
  if (node >= NN) return;
  int lane = threadIdx.x & 63;  // class index
  float m[8], z[8], acc[8], edl[8];
  #pragma unroll
  for (int h = 0; h < 8; h++) {
    m[h] = -INFINITY;
    z[h] = 0.f;
    acc[h] = 0.f;
    edl[h] = ed[node * NHEADS + h];
  }
  int beg = offs[node], end = offs[node + 1];
  for (int k = beg; k < end; k++) {
    int s = nbr[k];
    const float* hrow = h2 + (size_t)s * (NHEADS * NCLASS);
    const float* erow = es + s * NHEADS;
    #pragma unroll
    for (int h = 0; h < 8; h++) {
      float a = erow[h] + edl[h];
      a = (a > 0.f) ? a : 0.2f * a;
      float mn = fmaxf(m[h], a);
      float sc = __expf(m[h] - mn);
      float w = __expf(a - mn);
      float v = hrow[h * NCLASS + lane];
      acc[h] = acc[h] * sc + w * v;
      z[h] = z[h] * sc + w;
      m[h] = mn;
    }
  }
  float val = 0.f;
  #pragma unroll
  for (int h = 0; h < 8; h++) val += acc[h] / z[h];
  val = val * 0.125f + b2[lane];
  // log_softmax across the 64 lanes
  float mx = val;
  #pragma unroll
  for (int o = 32; o > 0; o >>= 1) mx = fmaxf(mx, __shfl_xor(mx, o));
  float ex = __expf(val - mx);
  float sm = ex;
  #pragma unroll
  for (int o = 32; o > 0; o >>= 1) sm += __shfl_xor(sm, o);
  out[(size_t)node * NCLASS + lane] = val - mx - __logf(sm);
}

// ---------------- launch ----------------
extern "C" void kernel_launch(void* const* d_in, const int* in_sizes, int n_in,
                              void* d_out, int out_size, void* d_ws, size_t ws_size,
                              hipStream_t stream) {
  const float* x   = (const float*)d_in[0];
  const int* eidx  = (const int*)d_in[1];
  const float* W1  = (const float*)d_in[2];
  const float* a1s = (const float*)d_in[3];
  const float* a1d = (const float*)d_in[4];
  const float* b1  = (const float*)d_in[5];
  const float* W2  = (const float*)d_in[6];
  const float* a2s = (const float*)d_in[7];
  const float* a2d = (const float*)d_in[8];
  const float* b2  = (const float*)d_in[9];
  const int E0 = in_sizes[1] / 2;
  const int* esrc = eidx;
  const int* edst = eidx + E0;

  // workspace carve (256B aligned)
  char* w = (char*)d_ws;
  auto carve = [&](size_t bytes) {
    void* p = (void*)w;
    w += (bytes + 255) & ~(size_t)255;
    return p;
  };
  int* deg     = (int*)carve((size_t)NN * 4);
  int* offs    = (int*)carve((size_t)(NN + 1) * 4);
  int* cursor  = (int*)carve((size_t)NN * 4);
  int* nbr     = (int*)carve((size_t)(E0 + NN) * 4);
  float* h1    = (float*)carve((size_t)NN * NHID * 4);
  float* es1   = (float*)carve((size_t)NN * NHEADS * 4);
  float* ed1   = (float*)carve((size_t)NN * NHEADS * 4);
  float* out1  = (float*)carve((size_t)NN * NHID * 4);
  float* h2    = (float*)carve((size_t)NN * NHEADS * NCLASS * 4);
  float* es2   = (float*)carve((size_t)NN * NHEADS * 4);
  float* ed2   = (float*)carve((size_t)NN * NHEADS * 4);

  // CSR build
  k_init_deg<<<(NN + 255) / 256, 256, 0, stream>>>(deg);
  k_count<<<(E0 + 255) / 256, 256, 0, stream>>>(edst, E0, deg);
  k_scan<<<1, 1024, 0, stream>>>(deg, offs, cursor);
  k_scatter<<<(E0 + NN + 255) / 256, 256, 0, stream>>>(esrc, edst, E0, cursor, nbr);

  // layer 1
  k_gemm<<<dim3((NN + 63) / 64, NHID / 64), 256, 0, stream>>>(x, W1, h1, NN, NF, NHID);
  k_escore<32><<<(NN * NHEADS + 255) / 256, 256, 0, stream>>>(h1, a1s, a1d, es1, ed1);
  k_agg1<<<(NN + 3) / 4, 256, 0, stream>>>(offs, nbr, h1, es1, ed1, b1, out1);

  // layer 2
  k_gemm<<<dim3((NN + 63) / 64, (NHEADS * NCLASS) / 64), 256, 0, stream>>>(
      out1, W2, h2, NN, NHID, NHEADS * NCLASS);
  k_escore<64><<<(NN * NHEADS + 255) / 256, 256, 0, stream>>>(h2, a2s, a2d, es2, ed2);
  k_agg2<<<(NN + 3) / 4, 256, 0, stream>>>(offs, nbr, h2, es2, ed2, b2, (float*)d_out);
}